// Round 12
// baseline (261.734 us; speedup 1.0000x reference)
//
#include <hip/hip_runtime.h>
#include <math.h>

#define NNODE 20000
#define NEDGE 160000
#define IN_DIMV 256
#define HIDV 128
#define DEGCAP 64
#define BAT 4

typedef __attribute__((ext_vector_type(8))) short bf16x8;
typedef __attribute__((ext_vector_type(4))) float f32x4;
typedef __attribute__((ext_vector_type(2))) float f32x2;

__device__ __forceinline__ float bf2f(unsigned short u) {
    union { unsigned int i; float f; } x; x.i = ((unsigned int)u) << 16; return x.f;
}
__device__ __forceinline__ unsigned short f2bf(float f) {
    union { float f; unsigned int i; } x; x.f = f;
    unsigned int r = x.i + 0x7fffu + ((x.i >> 16) & 1u);
    return (unsigned short)(r >> 16);
}
__device__ __forceinline__ void unpack8(uint4 p, float* f) {
    f[0] = bf2f((unsigned short)(p.x & 0xffff)); f[1] = bf2f((unsigned short)(p.x >> 16));
    f[2] = bf2f((unsigned short)(p.y & 0xffff)); f[3] = bf2f((unsigned short)(p.y >> 16));
    f[4] = bf2f((unsigned short)(p.z & 0xffff)); f[5] = bf2f((unsigned short)(p.z >> 16));
    f[6] = bf2f((unsigned short)(p.w & 0xffff)); f[7] = bf2f((unsigned short)(p.w >> 16));
}
__device__ __forceinline__ void unpack8f8_w(unsigned int a, unsigned int b, float* f) {
    f32x2 t;
    t = __builtin_amdgcn_cvt_pk_f32_fp8((int)a, false); f[0] = t.x; f[1] = t.y;
    t = __builtin_amdgcn_cvt_pk_f32_fp8((int)a, true);  f[2] = t.x; f[3] = t.y;
    t = __builtin_amdgcn_cvt_pk_f32_fp8((int)b, false); f[4] = t.x; f[5] = t.y;
    t = __builtin_amdgcn_cvt_pk_f32_fp8((int)b, true);  f[6] = t.x; f[7] = t.y;
}
__device__ __forceinline__ unsigned char f2fp8(float v) {
    int pk = __builtin_amdgcn_cvt_pk_fp8_f32(v, v, 0, false);
    return (unsigned char)(pk & 0xff);
}
__device__ __forceinline__ void gld_lds16(const unsigned short* g, unsigned short* l) {
    __builtin_amdgcn_global_load_lds((const __attribute__((address_space(1))) void*)g,
                                     (__attribute__((address_space(3))) void*)l, 16, 0, 0);
}

// ---------------- prep: zero cursor + convert lin_w (coalesced reads) ----------------
__global__ void prep_kernel(const float* __restrict__ lin_w,
                            unsigned short* __restrict__ arena, int* __restrict__ cursor)
{
    int idx = blockIdx.x * 256 + threadIdx.x;
    if (idx < NNODE) cursor[idx] = 0;
    int t = idx - NNODE;
    if (t < 0 || t >= 32768) return;
    int k = t >> 7;      // 0..255
    int n = t & 127;     // 0..127
    arena[n * 256 + k] = f2bf(lin_w[k * 128 + n]);
}

// ---------------- GEMM0 fused: 313 GEMM blocks (BM=64) + 416 aux blocks ----------------
__global__ __launch_bounds__(256) void gemm0_fused(
    const float* __restrict__ A, const unsigned short* __restrict__ WT,
    const float* __restrict__ b0, unsigned short* __restrict__ hbf_out,
    const float* __restrict__ qw0, const float* __restrict__ kw0,
    const float* __restrict__ vw0, const float* __restrict__ sw0,
    const float* __restrict__ qw1, const float* __restrict__ kw1,
    const float* __restrict__ vw1, const float* __restrict__ sw1,
    const int* __restrict__ ei, int* __restrict__ cursor, int* __restrict__ bucket,
    unsigned short* __restrict__ arena_big)
{
    __shared__ unsigned short smem[8192];   // 16 KB (GEMM path only)

    if (blockIdx.x >= 313) {
        int aux = (blockIdx.x - 313) * 256 + threadIdx.x;   // 0..106495
        {
            int e = aux;
            if (e < NEDGE) {
                int d = ei[NEDGE + e];
                int slot = atomicAdd(&cursor[d], 1);
                if (slot < DEGCAP) bucket[d * DEGCAP + slot] = ei[e];
            }
            e = aux + 106496;
            if (e < NEDGE) {
                int d = ei[NEDGE + e];
                int slot = atomicAdd(&cursor[d], 1);
                if (slot < DEGCAP) bucket[d * DEGCAP + slot] = ei[e];
            }
        }
#pragma unroll
        for (int pass = 0; pass < 4; pass++) {
            int t2 = aux + pass * 106496;
            int l = t2 / 212992;
            int r = t2 % 212992;
            int k = r / 1664;        // 0..127
            int n = r % 1664;        // 0..1663
            const float* qw = l ? qw1 : qw0;
            const float* kw = l ? kw1 : kw0;
            const float* vw = l ? vw1 : vw0;
            const float* sw = l ? sw1 : sw0;
            float v;
            if (n < 1536) {
                const float* w = (n < 512) ? qw : (n < 1024) ? kw : vw;
                v = w[k * 512 + (n & 511)];
            } else {
                v = sw[k * 128 + (n - 1536)];
            }
            arena_big[l * 212992 + n * 128 + k] = f2bf(v);
        }
        return;
    }

    unsigned short* As = smem;
    unsigned short* Bs = smem + 2048;
    unsigned short* ot = smem;
    const int K = 256;

    int tid = threadIdx.x;
    int lane = tid & 63;
    int w = tid >> 6;
    int bm = blockIdx.x * 64;

    int r0 = tid >> 2;
    int c0 = (tid & 3) * 8;
    int g0 = bm + r0; if (g0 > NNODE - 1) g0 = NNODE - 1;
    int srow = lane >> 2;
    int scol = (lane & 3) * 8;
    int sr0 = w * 32 + srow;
    int sr1 = w * 32 + 16 + srow;

    f32x4 acc[4][2] = {};
    int arow = lane & 15;
    int koff = (lane >> 4) * 8;

    for (int k0 = 0; k0 < K; k0 += 32) {
        {
            const float4* p0 = (const float4*)(A + (size_t)g0 * K + k0 + c0);
            float4 u = p0[0], v = p0[1];
            unsigned short t0[8] = {f2bf(u.x), f2bf(u.y), f2bf(u.z), f2bf(u.w),
                                    f2bf(v.x), f2bf(v.y), f2bf(v.z), f2bf(v.w)};
            *(uint4*)&As[r0 * 32 + c0] = *(uint4*)t0;
        }
        gld_lds16(WT + (size_t)sr0 * K + k0 + scol, Bs + sr0 * 32);
        gld_lds16(WT + (size_t)sr1 * K + k0 + scol, Bs + sr1 * 32);
        __syncthreads();
        bf16x8 fa[4], fb[2];
#pragma unroll
        for (int i = 0; i < 4; i++) fa[i] = *(const bf16x8*)&As[(arow + i * 16) * 32 + koff];
#pragma unroll
        for (int i = 0; i < 2; i++) fb[i] = *(const bf16x8*)&Bs[(w * 32 + i * 16 + arow) * 32 + koff];
#pragma unroll
        for (int mi = 0; mi < 4; mi++)
#pragma unroll
            for (int ni = 0; ni < 2; ni++)
                acc[mi][ni] = __builtin_amdgcn_mfma_f32_16x16x32_bf16(fa[mi], fb[ni], acc[mi][ni], 0, 0, 0);
        __syncthreads();
    }

    int quad = lane >> 4, lcol = lane & 15;
#pragma unroll
    for (int mi = 0; mi < 4; mi++) {
#pragma unroll
        for (int ni = 0; ni < 2; ni++) {
            int lc = w * 32 + ni * 16 + lcol;
            float bias = b0[lc];
#pragma unroll
            for (int reg = 0; reg < 4; reg++) {
                float v = fmaxf(acc[mi][ni][reg] + bias, 0.f);
                ot[(mi * 16 + quad * 4 + reg) * 128 + lc] = f2bf(v);
            }
        }
    }
    __syncthreads();
    int r = tid >> 2, q = tid & 3;
    int row = bm + r;
    if (row < NNODE) {
        uint4* dp = (uint4*)(hbf_out + (size_t)row * HIDV + q * 32);
        const uint4* sp = (const uint4*)(ot + r * 128 + q * 32);
#pragma unroll
        for (int qq = 0; qq < 4; qq++) dp[qq] = sp[qq];
    }
}

// ---------------- GEMM1 r25: one panel/block (313,13); W direct-to-register ----------------
// W passes through LDS with ZERO reuse (each element ds_read once by one lane),
// so skip the LDS round-trip: each lane loads its 8 fb fragments (16B each)
// straight from L2-hot WT (0.83 MB). Per (c,i) a wave reads 16 rows x 64B
// contiguous (half-line granules). LDS drops 48->16 KB (As only, reused as ot),
// stage drain covers only 4 A-DMAs -> ~5-6 blocks/CU for latency hiding.
// fb indexing bit-identical to the old Ws ds_read; same MFMA order.
__global__ __launch_bounds__(256) void mfma_gemm1(
    const unsigned short* __restrict__ A, const unsigned short* __restrict__ WT,
    const float* __restrict__ b0, const float* __restrict__ b1,
    const float* __restrict__ b2, const float* __restrict__ b3,
    unsigned short* __restrict__ qb_out, unsigned char* __restrict__ kv8_out,
    unsigned short* __restrict__ pre16_out)
{
    __shared__ unsigned short As[8192];    // 16 KB: A tile, then reused as epilogue tile
    unsigned short* ot = As;
    unsigned char* ot8 = (unsigned char*)As;
    const int K = 128;

    int tid = threadIdx.x;
    int lane = tid & 63;
    int w = tid >> 6;
    int bm = blockIdx.x * 64;
    int p = blockIdx.y;
    int bn = p * 128;

    int srow = lane >> 2;
    int scol = (lane & 3) * 8;
    int asr = w * 16 + srow;
    int aar = bm + asr; if (aar > NNODE - 1) aar = NNODE - 1;

    int arow = lane & 15;
    int koff = (lane >> 4) * 8;
    int quad = lane >> 4, lcol = lane & 15;

    // stage A tile (4 DMAs)
#pragma unroll
    for (int c = 0; c < 4; c++)
        gld_lds16(A + (size_t)aar * K + c * 32 + scol, As + c * 2048 + asr * 32);

    // direct per-lane W fragments (issued alongside the A DMA; L2-hot)
    bf16x8 fb[4][2];
#pragma unroll
    for (int c = 0; c < 4; c++)
#pragma unroll
        for (int i = 0; i < 2; i++)
            fb[c][i] = *(const bf16x8*)(WT + (size_t)(bn + w * 32 + i * 16 + arow) * K + c * 32 + koff);

    __syncthreads();   // A tile ready in LDS

    f32x4 acc[4][2] = {};
#pragma unroll
    for (int c = 0; c < 4; c++) {
        bf16x8 fa[4];
#pragma unroll
        for (int i = 0; i < 4; i++) fa[i] = *(const bf16x8*)&As[c * 2048 + (arow + i * 16) * 32 + koff];
#pragma unroll
        for (int mi = 0; mi < 4; mi++)
#pragma unroll
            for (int ni = 0; ni < 2; ni++)
                acc[mi][ni] = __builtin_amdgcn_mfma_f32_16x16x32_bf16(fa[mi], fb[c][ni], acc[mi][ni], 0, 0, 0);
    }
    __syncthreads();   // As dead; safe to reuse as ot

    if (p < 4 || p == 12) {
        const float* bb = (p < 4) ? (b0 + bn) : b3;
#pragma unroll
        for (int mi = 0; mi < 4; mi++) {
#pragma unroll
            for (int ni = 0; ni < 2; ni++) {
                int lc = w * 32 + ni * 16 + lcol;
                float bias = bb[lc];
#pragma unroll
                for (int reg = 0; reg < 4; reg++)
                    ot[(mi * 16 + quad * 4 + reg) * 128 + lc] = f2bf(acc[mi][ni][reg] + bias);
            }
        }
        __syncthreads();
        int r = tid >> 2, q = tid & 3;
        int row = bm + r;
        if (row < NNODE) {
            unsigned short* dst = (p < 4) ? (qb_out + (size_t)row * 512 + bn + q * 32)
                                          : (pre16_out + (size_t)row * HIDV + q * 32);
            const uint4* sp = (const uint4*)(ot + r * 128 + q * 32);
            uint4* dp = (uint4*)dst;
#pragma unroll
            for (int qq = 0; qq < 4; qq++) dp[qq] = sp[qq];
        }
    } else {
        const float* bb = (bn < 1024) ? (b1 + bn - 512) : (b2 + bn - 1024);
        int coff = bn - 512;
#pragma unroll
        for (int mi = 0; mi < 4; mi++) {
#pragma unroll
            for (int ni = 0; ni < 2; ni++) {
                int lc = w * 32 + ni * 16 + lcol;
                float bias = bb[lc];
#pragma unroll
                for (int reg = 0; reg < 4; reg++)
                    ot8[(mi * 16 + quad * 4 + reg) * 128 + lc] = f2fp8(acc[mi][ni][reg] + bias);
            }
        }
        __syncthreads();
        int r = tid >> 2, q = tid & 3;
        int row = bm + r;
        if (row < NNODE) {
            uint4* dp = (uint4*)(kv8_out + (size_t)row * 1024 + coff + q * 32);
            const uint4* sp = (const uint4*)(ot8 + r * 128 + q * 32);
            dp[0] = sp[0]; dp[1] = sp[1];
        }
    }
}

// ---------------- Fused attention + residual + LayerNorm (R10/R11 version: flat softmax) ----------------
__global__ __launch_bounds__(256) void attn_ln_kernel(
    const unsigned short* __restrict__ qb, const unsigned char* __restrict__ kv8,
    const int* __restrict__ cursor, const int* __restrict__ bucket,
    const unsigned short* __restrict__ pre16, const float* __restrict__ g,
    const float* __restrict__ b,
    unsigned short* __restrict__ hbf /* in: residual; out: LN result */,
    float* __restrict__ extout)
{
    int lane = threadIdx.x & 63;
    int wid = threadIdx.x >> 6;
    int i = blockIdx.x * 4 + wid;
    int myidx = bucket[i * DEGCAP + lane];            // speculative (independent of cursor)
    int cnt = cursor[i]; if (cnt > DEGCAP) cnt = DEGCAP;

    int hg = lane >> 4;
    int sl = lane & 15;
    int off = hg * 128 + sl * 8;

    size_t base = (size_t)i * HIDV + sl * 8;
    uint4 pv_raw = *(const uint4*)(pre16 + base);
    uint4 hv_raw = *(const uint4*)(hbf + base);

    float qr[8];
    {
        uint4 p = *(const uint4*)(qb + (size_t)i * 512 + lane * 8);
        unpack8(p, qr);
#pragma unroll
        for (int j = 0; j < 8; j++) qr[j] *= 0.0883883476483184f; // 1/sqrt(128)
    }

    float l = 0.f;
    float acc[8] = {0.f, 0.f, 0.f, 0.f, 0.f, 0.f, 0.f, 0.f};

    if (cnt > 0) {
        uint2 kA[BAT], vA[BAT], kB[BAT], vB[BAT];

        auto issue = [&](uint2 (&KB)[BAT], uint2 (&VB)[BAT], int bb) {
#pragma unroll
            for (int t = 0; t < BAT; t++) {
                int j = bb * BAT + t; if (j >= cnt) j = cnt - 1;
                int src = __shfl(myidx, j);
                const unsigned char* bp = kv8 + (size_t)src * 1024 + off;
                KB[t] = *(const uint2*)bp;
                VB[t] = *(const uint2*)(bp + 512);
            }
        };

        auto consume = [&](const uint2 (&KB)[BAT], const uint2 (&VB)[BAT], int bb) {
            int rem = cnt - bb * BAT;
            float d[BAT];
#pragma unroll
            for (int t = 0; t < BAT; t++) d[t] = -3.0e38f;
#pragma unroll
            for (int t = 0; t < BAT; t++) {
                if (t >= rem) break;
                float kf[8];
                unpack8f8_w(KB[t].x, KB[t].y, kf);
                d[t] = qr[0] * kf[0] + qr[1] * kf[1] + qr[2] * kf[2] + qr[3] * kf[3] +
                       qr[4] * kf[4] + qr[5] * kf[5] + qr[6] * kf[6] + qr[7] * kf[7];
            }
#pragma unroll
            for (int t = 0; t < BAT; t++) { if (t >= rem) break; d[t] += __shfl_xor(d[t], 8); }
#pragma unroll
            for (int t = 0; t < BAT; t++) { if (t >= rem) break; d[t] += __shfl_xor(d[t], 4); }
#pragma unroll
            for (int t = 0; t < BAT; t++) { if (t >= rem) break; d[t] += __shfl_xor(d[t], 2); }
#pragma unroll
            for (int t = 0; t < BAT; t++) { if (t >= rem) break; d[t] += __shfl_xor(d[t], 1); }

            // flat softmax: p = exp(d) directly (d bounded ~O(1); no overflow risk)
            float p[BAT];
#pragma unroll
            for (int t = 0; t < BAT; t++) p[t] = (t < rem) ? __expf(d[t]) : 0.f;
#pragma unroll
            for (int t = 0; t < BAT; t++) l += p[t];
#pragma unroll
            for (int t = 0; t < BAT; t++) {
                if (t >= rem) break;
                float vf[8];
                unpack8f8_w(VB[t].x, VB[t].y, vf);
                float pt = p[t];
#pragma unroll
                for (int c = 0; c < 8; c++) acc[c] += pt * vf[c];
            }
        };

        int nb = (cnt + BAT - 1) >> 2;
        issue(kA, vA, 0);
        for (int bb = 0; bb < nb; bb += 2) {
            if (bb + 1 < nb) issue(kB, vB, bb + 1);
            consume(kA, vA, bb);
            if (bb + 1 < nb) {
                if (bb + 2 < nb) issue(kA, vA, bb + 2);
                consume(kB, vB, bb + 1);
            }
        }
    }

    float linv = 0.25f / (l + 1e-16f);
#pragma unroll
    for (int c = 0; c < 8; c++) acc[c] *= linv;
#pragma unroll
    for (int c = 0; c < 8; c++) {
        acc[c] += __shfl_xor(acc[c], 16);
        acc[c] += __shfl_xor(acc[c], 32);
    }

    float pv[8], hv[8];
    unpack8(pv_raw, pv);
    unpack8(hv_raw, hv);
    float vals[8];
#pragma unroll
    for (int c = 0; c < 8; c++) vals[c] = acc[c] + pv[c] + hv[c];

    float s = 0.f;
#pragma unroll
    for (int c = 0; c < 8; c++) s += vals[c];
    s += __shfl_xor(s, 1); s += __shfl_xor(s, 2);
    s += __shfl_xor(s, 4); s += __shfl_xor(s, 8);
    float mu = s * (1.f / 128.f);
    float vs = 0.f;
#pragma unroll
    for (int c = 0; c < 8; c++) { float dx = vals[c] - mu; vs += dx * dx; }
    vs += __shfl_xor(vs, 1); vs += __shfl_xor(vs, 2);
    vs += __shfl_xor(vs, 4); vs += __shfl_xor(vs, 8);
    float rstd = rsqrtf(vs * (1.f / 128.f) + 1e-5f);

    float4 g0 = ((const float4*)(g + sl * 8))[0];
    float4 g1 = ((const float4*)(g + sl * 8))[1];
    float4 bb0 = ((const float4*)(b + sl * 8))[0];
    float4 bb1 = ((const float4*)(b + sl * 8))[1];
    float y[8];
    y[0] = (vals[0] - mu) * rstd * g0.x + bb0.x; y[1] = (vals[1] - mu) * rstd * g0.y + bb0.y;
    y[2] = (vals[2] - mu) * rstd * g0.z + bb0.z; y[3] = (vals[3] - mu) * rstd * g0.w + bb0.w;
    y[4] = (vals[4] - mu) * rstd * g1.x + bb1.x; y[5] = (vals[5] - mu) * rstd * g1.y + bb1.y;
    y[6] = (vals[6] - mu) * rstd * g1.z + bb1.z; y[7] = (vals[7] - mu) * rstd * g1.w + bb1.w;

    if (lane < 16) {
        unsigned short tmp[8] = {f2bf(y[0]), f2bf(y[1]), f2bf(y[2]), f2bf(y[3]),
                                 f2bf(y[4]), f2bf(y[5]), f2bf(y[6]), f2bf(y[7])};
        *(uint4*)(hbf + base) = *(uint4*)tmp;
        if (extout) {
            ((float4*)(extout + base))[0] = make_float4(y[0], y[1], y[2], y[3]);
            ((float4*)(extout + base))[1] = make_float4(y[4], y[5], y[6], y[7]);
        }
    }
}

extern "C" void kernel_launch(void* const* d_in, const int* in_sizes, int n_in,
                              void* d_out, int out_size, void* d_ws, size_t ws_size,
                              hipStream_t stream) {
    const float* x = (const float*)d_in[0];
    const int* ei = (const int*)d_in[1];

    char* ws = (char*)d_ws;
    unsigned short* hbf = (unsigned short*)(ws + 0);          // 5.12 MB
    unsigned short* pre16 = (unsigned short*)(ws + 5120000);  // 5.12 MB
    unsigned short* qb = (unsigned short*)(ws + 10240000);    // 20.48 MB (N x 512 bf16)
    unsigned char* kv8 = (unsigned char*)(ws + 30720000);     // 20.48 MB (N x 1024 fp8)
    int* cursor = (int*)(ws + 51200000);                      // 80 KB
    int* bucket = (int*)(ws + 51280000);                      // N x 64 ints = 5.12 MB
    unsigned short* arena = (unsigned short*)(ws + 56400000); // 0.92 MB

    prep_kernel<<<(NNODE + 32768 + 255) / 256, 256, 0, stream>>>(
        (const float*)d_in[2], arena, cursor);

    const int GM64 = (NNODE + 63) / 64; // 313

    gemm0_fused<<<GM64 + 416, 256, 0, stream>>>(
        x, arena, (const float*)d_in[3], hbf,
        (const float*)d_in[4], (const float*)d_in[6], (const float*)d_in[8], (const float*)d_in[10],
        (const float*)d_in[14], (const float*)d_in[16], (const float*)d_in[18], (const float*)d_in[20],
        ei, cursor, bucket, arena + 32768);

    for (int l = 0; l < 2; l++) {
        int o = 4 + l * 10;
        const unsigned short* WT = arena + 32768 + l * 212992;
        mfma_gemm1<<<dim3(GM64, 13), 256, 0, stream>>>(
            hbf, WT,
            (const float*)d_in[o + 1], (const float*)d_in[o + 3],
            (const float*)d_in[o + 5], (const float*)d_in[o + 7],
            qb, kv8, pre16);

        attn_ln_kernel<<<NNODE / 4, 256, 0, stream>>>(
            qb, kv8, cursor, bucket, pre16,
            (const float*)d_in[o + 8], (const float*)d_in[o + 9],
            hbf, (l == 1) ? (float*)d_out : nullptr);
    }
}